// Round 1
// baseline (1358.244 us; speedup 1.0000x reference)
//
#include <hip/hip_runtime.h>
#include <math.h>

namespace {

constexpr int Bb = 4, Ss = 256, Dd = 768, Vv = 50257;
constexpr int Mm = Bb * Ss;             // 1024 rows
constexpr int BM = 128, BN = 128, BK = 16;

// ---------------------------------------------------------------------------
// Kernel 1: t_sq[v] = sum_d W[v][d]^2   (one wave per vocab row)
// ---------------------------------------------------------------------------
__global__ __launch_bounds__(256) void tsq_kernel(const float* __restrict__ W,
                                                  float* __restrict__ tsq) {
    int gid  = blockIdx.x * blockDim.x + threadIdx.x;
    int wave = gid >> 6;
    int lane = threadIdx.x & 63;
    if (wave >= Vv) return;
    const float4* row = reinterpret_cast<const float4*>(W + (size_t)wave * Dd);
    float s = 0.f;
#pragma unroll
    for (int i = 0; i < 3; ++i) {            // 768/4 = 192 float4 = 64 lanes * 3
        float4 v = row[lane + 64 * i];
        s = fmaf(v.x, v.x, s);
        s = fmaf(v.y, v.y, s);
        s = fmaf(v.z, v.z, s);
        s = fmaf(v.w, v.w, s);
    }
#pragma unroll
    for (int off = 32; off > 0; off >>= 1) s += __shfl_down(s, off);
    if (lane == 0) tsq[wave] = s;
}

// ---------------------------------------------------------------------------
// Kernel 2: scores[m][n] = 2 * (A[m,:] . W[n,:]) - tsq[n]
// A: (1024, 768) row-major, W: (50257, 768) row-major  ("NT" GEMM)
// fp32 vector-ALU tiled GEMM: 128x128 tile, BK=16, 256 threads, 8x8 microtile
// ---------------------------------------------------------------------------
__global__ __launch_bounds__(256) void gemm_kernel(const float* __restrict__ A,
                                                   const float* __restrict__ W,
                                                   const float* __restrict__ tsq,
                                                   float* __restrict__ scores) {
    __shared__ float As[BK][BM + 4];
    __shared__ float Bs[BK][BN + 4];

    const int tid  = threadIdx.x;
    const int tx   = tid & 15;       // 0..15 -> N microtile
    const int ty   = tid >> 4;       // 0..15 -> M microtile
    const int row0 = blockIdx.y * BM;
    const int col0 = blockIdx.x * BN;

    // loader mapping: 512 float4 per (128x16) tile, 2 per thread
    const int lr = tid >> 2;         // 0..63 (row within tile; also +64)
    const int lk = (tid & 3) * 4;    // k offset 0,4,8,12

    float acc[8][8];
#pragma unroll
    for (int i = 0; i < 8; ++i)
#pragma unroll
        for (int j = 0; j < 8; ++j) acc[i][j] = 0.f;

    for (int k0 = 0; k0 < Dd; k0 += BK) {
        // global loads (regs) — M edge never OOB (1024 % 128 == 0), N edge guarded
        float4 a0 = *reinterpret_cast<const float4*>(&A[(size_t)(row0 + lr) * Dd + k0 + lk]);
        float4 a1 = *reinterpret_cast<const float4*>(&A[(size_t)(row0 + lr + 64) * Dd + k0 + lk]);
        float4 b0 = make_float4(0.f, 0.f, 0.f, 0.f);
        float4 b1 = make_float4(0.f, 0.f, 0.f, 0.f);
        const int c0r = col0 + lr, c1r = col0 + lr + 64;
        if (c0r < Vv) b0 = *reinterpret_cast<const float4*>(&W[(size_t)c0r * Dd + k0 + lk]);
        if (c1r < Vv) b1 = *reinterpret_cast<const float4*>(&W[(size_t)c1r * Dd + k0 + lk]);

        __syncthreads();   // previous iteration's compute done
        As[lk + 0][lr] = a0.x; As[lk + 1][lr] = a0.y;
        As[lk + 2][lr] = a0.z; As[lk + 3][lr] = a0.w;
        As[lk + 0][lr + 64] = a1.x; As[lk + 1][lr + 64] = a1.y;
        As[lk + 2][lr + 64] = a1.z; As[lk + 3][lr + 64] = a1.w;
        Bs[lk + 0][lr] = b0.x; Bs[lk + 1][lr] = b0.y;
        Bs[lk + 2][lr] = b0.z; Bs[lk + 3][lr] = b0.w;
        Bs[lk + 0][lr + 64] = b1.x; Bs[lk + 1][lr + 64] = b1.y;
        Bs[lk + 2][lr + 64] = b1.z; Bs[lk + 3][lr + 64] = b1.w;
        __syncthreads();

#pragma unroll
        for (int kk = 0; kk < BK; ++kk) {
            float a[8], b[8];
            *reinterpret_cast<float4*>(&a[0]) = *reinterpret_cast<const float4*>(&As[kk][ty * 8]);
            *reinterpret_cast<float4*>(&a[4]) = *reinterpret_cast<const float4*>(&As[kk][ty * 8 + 4]);
            *reinterpret_cast<float4*>(&b[0]) = *reinterpret_cast<const float4*>(&Bs[kk][tx * 8]);
            *reinterpret_cast<float4*>(&b[4]) = *reinterpret_cast<const float4*>(&Bs[kk][tx * 8 + 4]);
#pragma unroll
            for (int i = 0; i < 8; ++i)
#pragma unroll
                for (int j = 0; j < 8; ++j) acc[i][j] = fmaf(a[i], b[j], acc[i][j]);
        }
    }

    // epilogue: scores = 2*acc - tsq[n]
#pragma unroll
    for (int i = 0; i < 8; ++i) {
        const int gm = row0 + ty * 8 + i;
        const size_t base = (size_t)gm * Vv;
#pragma unroll
        for (int j = 0; j < 8; ++j) {
            const int gn = col0 + tx * 8 + j;
            if (gn < Vv) scores[base + gn] = fmaf(2.f, acc[i][j], -tsq[gn]);
        }
    }
}

// ---------------------------------------------------------------------------
// Kernel 3: per-row finalize. One block (256 thr) per row.
//  - pass1: max + argmax (first-occurrence tie-break, matches numpy argmax)
//  - pass2: sum of exp((s - max) * 10)
//  - pass3: out4 = normalized probs (in place over scores), out3 = one-hot
//  - tail:  out2 = float(pred); out0 = W[pred]; out1 = copy of A row
// ---------------------------------------------------------------------------
__global__ __launch_bounds__(256) void finalize_kernel(const float* __restrict__ A,
                                                       const float* __restrict__ W,
                                                       float* __restrict__ out0,
                                                       float* __restrict__ out1,
                                                       float* __restrict__ out2,
                                                       float* __restrict__ out3,
                                                       float* __restrict__ out4) {
    const int row = blockIdx.x;
    const int tid = threadIdx.x;
    float* srow = out4 + (size_t)row * Vv;   // raw scores in, probs out
    float* hrow = out3 + (size_t)row * Vv;   // one-hot out

    __shared__ float smax[256];
    __shared__ int   sidx[256];
    __shared__ float ssum[256];

    float m = -INFINITY;
    int   idx = 0x7fffffff;
    for (int i = tid; i < Vv; i += 256) {
        const float s = srow[i];
        if (s > m) { m = s; idx = i; }       // strict > keeps lowest index in-stride
    }
    smax[tid] = m;
    sidx[tid] = idx;
    __syncthreads();
#pragma unroll
    for (int off = 128; off > 0; off >>= 1) {
        if (tid < off) {
            const float m2 = smax[tid + off];
            const int   i2 = sidx[tid + off];
            if (m2 > smax[tid] || (m2 == smax[tid] && i2 < sidx[tid])) {
                smax[tid] = m2;
                sidx[tid] = i2;
            }
        }
        __syncthreads();
    }
    const float gmax = smax[0];
    const int   pred = sidx[0];
    __syncthreads();

    float sum = 0.f;
    for (int i = tid; i < Vv; i += 256) sum += expf((srow[i] - gmax) * 10.0f);
    ssum[tid] = sum;
    __syncthreads();
#pragma unroll
    for (int off = 128; off > 0; off >>= 1) {
        if (tid < off) ssum[tid] += ssum[tid + off];
        __syncthreads();
    }
    const float inv = 1.0f / ssum[0];

    for (int i = tid; i < Vv; i += 256) {
        const float e = expf((srow[i] - gmax) * 10.0f) * inv;
        srow[i] = e;
        hrow[i] = (i == pred) ? 1.0f : 0.0f;
    }

    if (tid == 0) out2[row] = (float)pred;
    for (int j = tid; j < Dd; j += 256) {
        out0[(size_t)row * Dd + j] = W[(size_t)pred * Dd + j];
        out1[(size_t)row * Dd + j] = A[(size_t)row * Dd + j];
    }
}

}  // namespace

extern "C" void kernel_launch(void* const* d_in, const int* in_sizes, int n_in,
                              void* d_out, int out_size, void* d_ws, size_t ws_size,
                              hipStream_t stream) {
    const float* pred_embeds  = (const float*)d_in[0];   // (4,256,768)
    const float* embed_weight = (const float*)d_in[1];   // (50257,768)

    float* out  = (float*)d_out;
    float* out0 = out;                                    // (B,S,D) straight-through embeds
    float* out1 = out0 + (size_t)Mm * Dd;                 // (B,S,D) pred_embeds copy
    float* out2 = out1 + (size_t)Mm * Dd;                 // (B,S)   predictions (as float)
    float* out3 = out2 + Mm;                              // (B,S,V) one-hot
    float* out4 = out3 + (size_t)Mm * Vv;                 // (B,S,V) softmax probs

    // tsq scratch: prefer d_ws; fall back to out3 region (overwritten later in-order)
    float* tsq = (ws_size >= (size_t)Vv * sizeof(float)) ? (float*)d_ws : out3;

    tsq_kernel<<<(Vv + 3) / 4, 256, 0, stream>>>(embed_weight, tsq);

    dim3 grid((Vv + BN - 1) / BN, Mm / BM);   // 393 x 8
    gemm_kernel<<<grid, 256, 0, stream>>>(pred_embeds, embed_weight, tsq, out4);

    finalize_kernel<<<Mm, 256, 0, stream>>>(pred_embeds, embed_weight,
                                            out0, out1, out2, out3, out4);
}

// Round 2
// 672.728 us; speedup vs baseline: 2.0190x; 2.0190x over previous
//
#include <hip/hip_runtime.h>
#include <math.h>

namespace {

constexpr int Bb = 4, Ss = 256, Dd = 768, Vv = 50257;
constexpr int Mm = Bb * Ss;             // 1024 rows
constexpr int BM = 128, BN = 128, BK = 32;
constexpr int NSTEP = Dd / BK;          // 24
constexpr int LDP = 40;                 // padded row stride (f16 elems) = 80 B

typedef _Float16 f16x8 __attribute__((ext_vector_type(8)));
typedef float f32x4 __attribute__((ext_vector_type(4)));

// ---------------------------------------------------------------------------
// Kernel 1: t_sq[v] = sum_d W[v][d]^2   (one wave per vocab row)
// ---------------------------------------------------------------------------
__global__ __launch_bounds__(256) void tsq_kernel(const float* __restrict__ W,
                                                  float* __restrict__ tsq) {
    int gid  = blockIdx.x * blockDim.x + threadIdx.x;
    int wave = gid >> 6;
    int lane = threadIdx.x & 63;
    if (wave >= Vv) return;
    const float4* row = reinterpret_cast<const float4*>(W + (size_t)wave * Dd);
    float s = 0.f;
#pragma unroll
    for (int i = 0; i < 3; ++i) {
        float4 v = row[lane + 64 * i];
        s = fmaf(v.x, v.x, s);
        s = fmaf(v.y, v.y, s);
        s = fmaf(v.z, v.z, s);
        s = fmaf(v.w, v.w, s);
    }
#pragma unroll
    for (int off = 32; off > 0; off >>= 1) s += __shfl_down(s, off);
    if (lane == 0) tsq[wave] = s;
}

// ---------------------------------------------------------------------------
// Kernel 2: scores[m][n] = 2 * (A[m,:] . W[n,:]) - tsq[n]   via split-f16 MFMA
// A: (1024,768) row-major, W: (50257,768) row-major ("NT" GEMM)
// 128x128x32 tile, 4 waves (2x2), 64x64 per wave, 3 MFMAs per frag per K-step
// ---------------------------------------------------------------------------
__global__ __launch_bounds__(256) void gemm_kernel(const float* __restrict__ A,
                                                   const float* __restrict__ W,
                                                   const float* __restrict__ tsq,
                                                   float* __restrict__ scores) {
    __shared__ _Float16 Ah[BM][LDP];
    __shared__ _Float16 Al[BM][LDP];
    __shared__ _Float16 Wh[BN][LDP];
    __shared__ _Float16 Wl[BN][LDP];

    const int tid  = threadIdx.x;
    const int row0 = blockIdx.y * BM;
    const int col0 = blockIdx.x * BN;

    // loader mapping: 2 threads per tile-row, 16 floats (64B) each
    const int lr   = tid >> 1;            // 0..127: tile row
    const int lk   = (tid & 1) * 16;      // k offset 0 or 16

    // wave/fragment mapping
    const int wid  = tid >> 6;            // 0..3
    const int lane = tid & 63;
    const int wr   = wid >> 1;            // wave row (0..1) -> 64 rows
    const int wc   = wid & 1;             // wave col (0..1) -> 64 cols
    const int fr   = lane & 15;           // fragment row/col index
    const int fq   = lane >> 4;           // k-group 0..3 (8 elems each)

    float4 ra[4], rw[4];
    const bool wvalid = (col0 + lr) < Vv;

    auto load_tiles = [&](int k0) {
        const float* ap = &A[(size_t)(row0 + lr) * Dd + k0 + lk];
        ra[0] = *reinterpret_cast<const float4*>(ap + 0);
        ra[1] = *reinterpret_cast<const float4*>(ap + 4);
        ra[2] = *reinterpret_cast<const float4*>(ap + 8);
        ra[3] = *reinterpret_cast<const float4*>(ap + 12);
        if (wvalid) {
            const float* wp = &W[(size_t)(col0 + lr) * Dd + k0 + lk];
            rw[0] = *reinterpret_cast<const float4*>(wp + 0);
            rw[1] = *reinterpret_cast<const float4*>(wp + 4);
            rw[2] = *reinterpret_cast<const float4*>(wp + 8);
            rw[3] = *reinterpret_cast<const float4*>(wp + 12);
        } else {
            rw[0] = rw[1] = rw[2] = rw[3] = make_float4(0.f, 0.f, 0.f, 0.f);
        }
    };

    auto store_tiles = [&]() {
        _Float16 hi[16], lo[16];
        const float* fa = reinterpret_cast<const float*>(ra);
#pragma unroll
        for (int i = 0; i < 16; ++i) {
            const float v = fa[i];
            const _Float16 h = (_Float16)v;
            hi[i] = h;
            lo[i] = (_Float16)(v - (float)h);
        }
        *reinterpret_cast<f16x8*>(&Ah[lr][lk])     = *reinterpret_cast<const f16x8*>(&hi[0]);
        *reinterpret_cast<f16x8*>(&Ah[lr][lk + 8]) = *reinterpret_cast<const f16x8*>(&hi[8]);
        *reinterpret_cast<f16x8*>(&Al[lr][lk])     = *reinterpret_cast<const f16x8*>(&lo[0]);
        *reinterpret_cast<f16x8*>(&Al[lr][lk + 8]) = *reinterpret_cast<const f16x8*>(&lo[8]);
        const float* fw = reinterpret_cast<const float*>(rw);
#pragma unroll
        for (int i = 0; i < 16; ++i) {
            const float v = fw[i];
            const _Float16 h = (_Float16)v;
            hi[i] = h;
            lo[i] = (_Float16)(v - (float)h);
        }
        *reinterpret_cast<f16x8*>(&Wh[lr][lk])     = *reinterpret_cast<const f16x8*>(&hi[0]);
        *reinterpret_cast<f16x8*>(&Wh[lr][lk + 8]) = *reinterpret_cast<const f16x8*>(&hi[8]);
        *reinterpret_cast<f16x8*>(&Wl[lr][lk])     = *reinterpret_cast<const f16x8*>(&lo[0]);
        *reinterpret_cast<f16x8*>(&Wl[lr][lk + 8]) = *reinterpret_cast<const f16x8*>(&lo[8]);
    };

    f32x4 acc[4][4];
#pragma unroll
    for (int m = 0; m < 4; ++m)
#pragma unroll
        for (int n = 0; n < 4; ++n) acc[m][n] = (f32x4){0.f, 0.f, 0.f, 0.f};

    load_tiles(0);
    for (int step = 0; step < NSTEP; ++step) {
        __syncthreads();          // previous compute done, LDS free
        store_tiles();            // convert + ds_write this step's tiles
        __syncthreads();
        if (step + 1 < NSTEP) load_tiles((step + 1) * BK);   // prefetch next

        f16x8 ah[4], al[4];
#pragma unroll
        for (int m = 0; m < 4; ++m) {
            const int r = wr * 64 + m * 16 + fr;
            ah[m] = *reinterpret_cast<const f16x8*>(&Ah[r][fq * 8]);
            al[m] = *reinterpret_cast<const f16x8*>(&Al[r][fq * 8]);
        }
#pragma unroll
        for (int n = 0; n < 4; ++n) {
            const int c = wc * 64 + n * 16 + fr;
            const f16x8 bh = *reinterpret_cast<const f16x8*>(&Wh[c][fq * 8]);
            const f16x8 bl = *reinterpret_cast<const f16x8*>(&Wl[c][fq * 8]);
#pragma unroll
            for (int m = 0; m < 4; ++m) {
                acc[m][n] = __builtin_amdgcn_mfma_f32_16x16x32_f16(ah[m], bh, acc[m][n], 0, 0, 0);
                acc[m][n] = __builtin_amdgcn_mfma_f32_16x16x32_f16(al[m], bh, acc[m][n], 0, 0, 0);
                acc[m][n] = __builtin_amdgcn_mfma_f32_16x16x32_f16(ah[m], bl, acc[m][n], 0, 0, 0);
            }
        }
    }

    // epilogue: scores = 2*acc - tsq[n]
    // C/D mapping: col = lane&15 (fr), row = (lane>>4)*4 + reg (fq*4+r)
#pragma unroll
    for (int n = 0; n < 4; ++n) {
        const int gn = col0 + wc * 64 + n * 16 + fr;
        if (gn >= Vv) continue;
        const float t = tsq[gn];
#pragma unroll
        for (int m = 0; m < 4; ++m) {
            const int gm = row0 + wr * 64 + m * 16 + fq * 4;
#pragma unroll
            for (int r = 0; r < 4; ++r) {
                scores[(size_t)(gm + r) * Vv + gn] = fmaf(2.f, acc[m][n][r], -t);
            }
        }
    }
}

// ---------------------------------------------------------------------------
// Kernel 3: per-row finalize (unchanged from round 1 — passed)
// ---------------------------------------------------------------------------
__global__ __launch_bounds__(256) void finalize_kernel(const float* __restrict__ A,
                                                       const float* __restrict__ W,
                                                       float* __restrict__ out0,
                                                       float* __restrict__ out1,
                                                       float* __restrict__ out2,
                                                       float* __restrict__ out3,
                                                       float* __restrict__ out4) {
    const int row = blockIdx.x;
    const int tid = threadIdx.x;
    float* srow = out4 + (size_t)row * Vv;   // raw scores in, probs out
    float* hrow = out3 + (size_t)row * Vv;   // one-hot out

    __shared__ float smax[256];
    __shared__ int   sidx[256];
    __shared__ float ssum[256];

    float m = -INFINITY;
    int   idx = 0x7fffffff;
    for (int i = tid; i < Vv; i += 256) {
        const float s = srow[i];
        if (s > m) { m = s; idx = i; }       // strict > keeps lowest index in-stride
    }
    smax[tid] = m;
    sidx[tid] = idx;
    __syncthreads();
#pragma unroll
    for (int off = 128; off > 0; off >>= 1) {
        if (tid < off) {
            const float m2 = smax[tid + off];
            const int   i2 = sidx[tid + off];
            if (m2 > smax[tid] || (m2 == smax[tid] && i2 < sidx[tid])) {
                smax[tid] = m2;
                sidx[tid] = i2;
            }
        }
        __syncthreads();
    }
    const float gmax = smax[0];
    const int   pred = sidx[0];
    __syncthreads();

    float sum = 0.f;
    for (int i = tid; i < Vv; i += 256) sum += expf((srow[i] - gmax) * 10.0f);
    ssum[tid] = sum;
    __syncthreads();
#pragma unroll
    for (int off = 128; off > 0; off >>= 1) {
        if (tid < off) ssum[tid] += ssum[tid + off];
        __syncthreads();
    }
    const float inv = 1.0f / ssum[0];

    for (int i = tid; i < Vv; i += 256) {
        const float e = expf((srow[i] - gmax) * 10.0f) * inv;
        srow[i] = e;
        hrow[i] = (i == pred) ? 1.0f : 0.0f;
    }

    if (tid == 0) out2[row] = (float)pred;
    for (int j = tid; j < Dd; j += 256) {
        out0[(size_t)row * Dd + j] = W[(size_t)pred * Dd + j];
        out1[(size_t)row * Dd + j] = A[(size_t)row * Dd + j];
    }
}

}  // namespace

extern "C" void kernel_launch(void* const* d_in, const int* in_sizes, int n_in,
                              void* d_out, int out_size, void* d_ws, size_t ws_size,
                              hipStream_t stream) {
    const float* pred_embeds  = (const float*)d_in[0];   // (4,256,768)
    const float* embed_weight = (const float*)d_in[1];   // (50257,768)

    float* out  = (float*)d_out;
    float* out0 = out;                                    // (B,S,D) straight-through embeds
    float* out1 = out0 + (size_t)Mm * Dd;                 // (B,S,D) pred_embeds copy
    float* out2 = out1 + (size_t)Mm * Dd;                 // (B,S)   predictions (as float)
    float* out3 = out2 + Mm;                              // (B,S,V) one-hot
    float* out4 = out3 + (size_t)Mm * Vv;                 // (B,S,V) softmax probs

    float* tsq = (ws_size >= (size_t)Vv * sizeof(float)) ? (float*)d_ws : out3;

    tsq_kernel<<<(Vv + 3) / 4, 256, 0, stream>>>(embed_weight, tsq);

    dim3 grid((Vv + BN - 1) / BN, Mm / BM);   // 393 x 8
    gemm_kernel<<<grid, 256, 0, stream>>>(pred_embeds, embed_weight, tsq, out4);

    finalize_kernel<<<Mm, 256, 0, stream>>>(pred_embeds, embed_weight,
                                            out0, out1, out2, out3, out4);
}

// Round 3
// 523.208 us; speedup vs baseline: 2.5960x; 1.2858x over previous
//
#include <hip/hip_runtime.h>
#include <math.h>

namespace {

constexpr int Bb = 4, Ss = 256, Dd = 768, Vv = 50257;
constexpr int Mm = Bb * Ss;             // 1024 rows
constexpr int BM = 128, BN = 128, BK = 32;
constexpr int NSTEP = Dd / BK;          // 24
constexpr int LDP = 40;                 // padded row stride (f16 elems) = 80 B
constexpr float SC = 14.4269504088896341f;   // 10 * log2(e): exp(10x) = exp2(SC*x)

typedef _Float16 f16x8 __attribute__((ext_vector_type(8)));
typedef float f32x4 __attribute__((ext_vector_type(4)));

// ---------------------------------------------------------------------------
// Kernel 1: t_sq[v] = sum_d W[v][d]^2   (one wave per vocab row)
// ---------------------------------------------------------------------------
__global__ __launch_bounds__(256) void tsq_kernel(const float* __restrict__ W,
                                                  float* __restrict__ tsq) {
    int gid  = blockIdx.x * blockDim.x + threadIdx.x;
    int wave = gid >> 6;
    int lane = threadIdx.x & 63;
    if (wave >= Vv) return;
    const float4* row = reinterpret_cast<const float4*>(W + (size_t)wave * Dd);
    float s = 0.f;
#pragma unroll
    for (int i = 0; i < 3; ++i) {
        float4 v = row[lane + 64 * i];
        s = fmaf(v.x, v.x, s);
        s = fmaf(v.y, v.y, s);
        s = fmaf(v.z, v.z, s);
        s = fmaf(v.w, v.w, s);
    }
#pragma unroll
    for (int off = 32; off > 0; off >>= 1) s += __shfl_down(s, off);
    if (lane == 0) tsq[wave] = s;
}

// ---------------------------------------------------------------------------
// Kernel 2: scores[m][n] = 2 * (A[m,:] . W[n,:]) - tsq[n]   via split-f16 MFMA
// (unchanged from round 2 — ~300 us, next round's target)
// ---------------------------------------------------------------------------
__global__ __launch_bounds__(256) void gemm_kernel(const float* __restrict__ A,
                                                   const float* __restrict__ W,
                                                   const float* __restrict__ tsq,
                                                   float* __restrict__ scores) {
    __shared__ _Float16 Ah[BM][LDP];
    __shared__ _Float16 Al[BM][LDP];
    __shared__ _Float16 Wh[BN][LDP];
    __shared__ _Float16 Wl[BN][LDP];

    const int tid  = threadIdx.x;
    const int row0 = blockIdx.y * BM;
    const int col0 = blockIdx.x * BN;

    const int lr   = tid >> 1;            // 0..127: tile row
    const int lk   = (tid & 1) * 16;      // k offset 0 or 16

    const int wid  = tid >> 6;            // 0..3
    const int lane = tid & 63;
    const int wr   = wid >> 1;
    const int wc   = wid & 1;
    const int fr   = lane & 15;
    const int fq   = lane >> 4;

    float4 ra[4], rw[4];
    const bool wvalid = (col0 + lr) < Vv;

    auto load_tiles = [&](int k0) {
        const float* ap = &A[(size_t)(row0 + lr) * Dd + k0 + lk];
        ra[0] = *reinterpret_cast<const float4*>(ap + 0);
        ra[1] = *reinterpret_cast<const float4*>(ap + 4);
        ra[2] = *reinterpret_cast<const float4*>(ap + 8);
        ra[3] = *reinterpret_cast<const float4*>(ap + 12);
        if (wvalid) {
            const float* wp = &W[(size_t)(col0 + lr) * Dd + k0 + lk];
            rw[0] = *reinterpret_cast<const float4*>(wp + 0);
            rw[1] = *reinterpret_cast<const float4*>(wp + 4);
            rw[2] = *reinterpret_cast<const float4*>(wp + 8);
            rw[3] = *reinterpret_cast<const float4*>(wp + 12);
        } else {
            rw[0] = rw[1] = rw[2] = rw[3] = make_float4(0.f, 0.f, 0.f, 0.f);
        }
    };

    auto store_tiles = [&]() {
        _Float16 hi[16], lo[16];
        const float* fa = reinterpret_cast<const float*>(ra);
#pragma unroll
        for (int i = 0; i < 16; ++i) {
            const float v = fa[i];
            const _Float16 h = (_Float16)v;
            hi[i] = h;
            lo[i] = (_Float16)(v - (float)h);
        }
        *reinterpret_cast<f16x8*>(&Ah[lr][lk])     = *reinterpret_cast<const f16x8*>(&hi[0]);
        *reinterpret_cast<f16x8*>(&Ah[lr][lk + 8]) = *reinterpret_cast<const f16x8*>(&hi[8]);
        *reinterpret_cast<f16x8*>(&Al[lr][lk])     = *reinterpret_cast<const f16x8*>(&lo[0]);
        *reinterpret_cast<f16x8*>(&Al[lr][lk + 8]) = *reinterpret_cast<const f16x8*>(&lo[8]);
        const float* fw = reinterpret_cast<const float*>(rw);
#pragma unroll
        for (int i = 0; i < 16; ++i) {
            const float v = fw[i];
            const _Float16 h = (_Float16)v;
            hi[i] = h;
            lo[i] = (_Float16)(v - (float)h);
        }
        *reinterpret_cast<f16x8*>(&Wh[lr][lk])     = *reinterpret_cast<const f16x8*>(&hi[0]);
        *reinterpret_cast<f16x8*>(&Wh[lr][lk + 8]) = *reinterpret_cast<const f16x8*>(&hi[8]);
        *reinterpret_cast<f16x8*>(&Wl[lr][lk])     = *reinterpret_cast<const f16x8*>(&lo[0]);
        *reinterpret_cast<f16x8*>(&Wl[lr][lk + 8]) = *reinterpret_cast<const f16x8*>(&lo[8]);
    };

    f32x4 acc[4][4];
#pragma unroll
    for (int m = 0; m < 4; ++m)
#pragma unroll
        for (int n = 0; n < 4; ++n) acc[m][n] = (f32x4){0.f, 0.f, 0.f, 0.f};

    load_tiles(0);
    for (int step = 0; step < NSTEP; ++step) {
        __syncthreads();
        store_tiles();
        __syncthreads();
        if (step + 1 < NSTEP) load_tiles((step + 1) * BK);

        f16x8 ah[4], al[4];
#pragma unroll
        for (int m = 0; m < 4; ++m) {
            const int r = wr * 64 + m * 16 + fr;
            ah[m] = *reinterpret_cast<const f16x8*>(&Ah[r][fq * 8]);
            al[m] = *reinterpret_cast<const f16x8*>(&Al[r][fq * 8]);
        }
#pragma unroll
        for (int n = 0; n < 4; ++n) {
            const int c = wc * 64 + n * 16 + fr;
            const f16x8 bh = *reinterpret_cast<const f16x8*>(&Wh[c][fq * 8]);
            const f16x8 bl = *reinterpret_cast<const f16x8*>(&Wl[c][fq * 8]);
#pragma unroll
            for (int m = 0; m < 4; ++m) {
                acc[m][n] = __builtin_amdgcn_mfma_f32_16x16x32_f16(ah[m], bh, acc[m][n], 0, 0, 0);
                acc[m][n] = __builtin_amdgcn_mfma_f32_16x16x32_f16(al[m], bh, acc[m][n], 0, 0, 0);
                acc[m][n] = __builtin_amdgcn_mfma_f32_16x16x32_f16(ah[m], bl, acc[m][n], 0, 0, 0);
            }
        }
    }

#pragma unroll
    for (int n = 0; n < 4; ++n) {
        const int gn = col0 + wc * 64 + n * 16 + fr;
        if (gn >= Vv) continue;
        const float t = tsq[gn];
#pragma unroll
        for (int m = 0; m < 4; ++m) {
            const int gm = row0 + wr * 64 + m * 16 + fq * 4;
#pragma unroll
            for (int r = 0; r < 4; ++r) {
                scores[(size_t)(gm + r) * Vv + gn] = fmaf(2.f, acc[m][n][r], -t);
            }
        }
    }
}

// ---------------------------------------------------------------------------
// Kernel 3: per-row finalize, vectorized float4, 2 passes.
//  pass1: ONLINE max+argmax+exp-sum in a single read (rescale on new max;
//         ascending-index strict-> keeps numpy first-occurrence argmax)
//  pass2: probs (in place) + one-hot, float4 stores
// ---------------------------------------------------------------------------
__global__ __launch_bounds__(256) void finalize_kernel(const float* __restrict__ A,
                                                       const float* __restrict__ W,
                                                       float* __restrict__ out0,
                                                       float* __restrict__ out1,
                                                       float* __restrict__ out2,
                                                       float* __restrict__ out3,
                                                       float* __restrict__ out4) {
    const int row = blockIdx.x;
    const int tid = threadIdx.x;
    float* srow = out4 + (size_t)row * Vv;   // raw scores in, probs out (in place)
    float* hrow = out3 + (size_t)row * Vv;   // one-hot out
    constexpr int NV4 = Vv >> 2;             // 12564 float4; tail elem 50256

    const float4* s4 = reinterpret_cast<const float4*>(srow);

    float m = -INFINITY;
    int   idx = 0;
    float sum = 0.f;
    for (int i = tid; i < NV4; i += 256) {
        const float4 v = s4[i];
        const float vv[4] = {v.x, v.y, v.z, v.w};
#pragma unroll
        for (int j = 0; j < 4; ++j) {
            const float val = vv[j];
            if (val > m) {                   // rare after warm-up
                sum *= exp2f((m - val) * SC);
                m = val;
                idx = 4 * i + j;
            }
            sum += exp2f((val - m) * SC);
        }
    }
    if (tid == 0) {                          // tail element Vv-1
        const float val = srow[Vv - 1];
        if (val > m) { sum *= exp2f((m - val) * SC); m = val; idx = Vv - 1; }
        sum += exp2f((val - m) * SC);
    }

    __shared__ float smax[256];
    __shared__ int   sidx[256];
    __shared__ float ssum[256];
    smax[tid] = m; sidx[tid] = idx; ssum[tid] = sum;
    __syncthreads();
#pragma unroll
    for (int off = 128; off > 0; off >>= 1) {
        if (tid < off) {
            const float m1 = smax[tid], m2 = smax[tid + off];
            const int   i1 = sidx[tid], i2 = sidx[tid + off];
            const float s1 = ssum[tid], s2 = ssum[tid + off];
            if (m2 > m1 || (m2 == m1 && i2 < i1)) {
                smax[tid] = m2; sidx[tid] = i2;
                ssum[tid] = s1 * exp2f((m1 - m2) * SC) + s2;
            } else {
                ssum[tid] = s1 + s2 * exp2f((m2 - m1) * SC);
            }
        }
        __syncthreads();
    }
    const float gmax = smax[0];
    const int   pred = sidx[0];
    const float inv  = 1.0f / ssum[0];
    __syncthreads();

    // pass2: vectorized writeout (probs in place, one-hot)
    float4* p4 = reinterpret_cast<float4*>(srow);
    float4* h4 = reinterpret_cast<float4*>(hrow);
    for (int i = tid; i < NV4; i += 256) {
        const float4 v = s4[i];
        const int b = 4 * i;
        float4 p, h;
        p.x = exp2f((v.x - gmax) * SC) * inv;
        p.y = exp2f((v.y - gmax) * SC) * inv;
        p.z = exp2f((v.z - gmax) * SC) * inv;
        p.w = exp2f((v.w - gmax) * SC) * inv;
        h.x = (b + 0 == pred) ? 1.f : 0.f;
        h.y = (b + 1 == pred) ? 1.f : 0.f;
        h.z = (b + 2 == pred) ? 1.f : 0.f;
        h.w = (b + 3 == pred) ? 1.f : 0.f;
        p4[i] = p;
        h4[i] = h;
    }
    if (tid == 0) {
        const float val = srow[Vv - 1];
        srow[Vv - 1] = exp2f((val - gmax) * SC) * inv;
        hrow[Vv - 1] = (pred == Vv - 1) ? 1.f : 0.f;
        out2[row] = (float)pred;
    }

    // small row outputs: out0 = W[pred], out1 = copy of A row (192 float4)
    const float4* wrow = reinterpret_cast<const float4*>(W + (size_t)pred * Dd);
    const float4* arow = reinterpret_cast<const float4*>(A + (size_t)row * Dd);
    float4* o0 = reinterpret_cast<float4*>(out0 + (size_t)row * Dd);
    float4* o1 = reinterpret_cast<float4*>(out1 + (size_t)row * Dd);
    if (tid < Dd / 4) {
        o0[tid] = wrow[tid];
        o1[tid] = arow[tid];
    }
}

}  // namespace

extern "C" void kernel_launch(void* const* d_in, const int* in_sizes, int n_in,
                              void* d_out, int out_size, void* d_ws, size_t ws_size,
                              hipStream_t stream) {
    const float* pred_embeds  = (const float*)d_in[0];   // (4,256,768)
    const float* embed_weight = (const float*)d_in[1];   // (50257,768)

    float* out  = (float*)d_out;
    float* out0 = out;                                    // (B,S,D) straight-through embeds
    float* out1 = out0 + (size_t)Mm * Dd;                 // (B,S,D) pred_embeds copy
    float* out2 = out1 + (size_t)Mm * Dd;                 // (B,S)   predictions (as float)
    float* out3 = out2 + Mm;                              // (B,S,V) one-hot
    float* out4 = out3 + (size_t)Mm * Vv;                 // (B,S,V) softmax probs

    float* tsq = (ws_size >= (size_t)Vv * sizeof(float)) ? (float*)d_ws : out3;

    tsq_kernel<<<(Vv + 3) / 4, 256, 0, stream>>>(embed_weight, tsq);

    dim3 grid((Vv + BN - 1) / BN, Mm / BM);   // 393 x 8
    gemm_kernel<<<grid, 256, 0, stream>>>(pred_embeds, embed_weight, tsq, out4);

    finalize_kernel<<<Mm, 256, 0, stream>>>(pred_embeds, embed_weight,
                                            out0, out1, out2, out3, out4);
}